// Round 1
// baseline (885.370 us; speedup 1.0000x reference)
//
#include <hip/hip_runtime.h>
#include <math.h>

#define L_TOT 36864
#define LCHUNK 144
#define NCHUNK 256
#define BN_EPS 1e-5f

__device__ __forceinline__ float fsigmoid(float x){ return 1.f/(1.f+__expf(-x)); }
__device__ __forceinline__ float fsoftplus(float x){ return (x>20.f)? x : log1pf(__expf(x)); }

// ---------------- K1: LayerNorm + in-proj (xz = xn @ in_w.T, split into xs/z) ----
// x input feature-major [c][t]; for DIM==32 channels 16..31 come from x1.
template<int DIM, int DI>
__global__ void k_front(const float* __restrict__ x0, const float* __restrict__ x1,
                        const float* __restrict__ lnw, const float* __restrict__ lnb,
                        const float* __restrict__ inw,
                        float* __restrict__ xs, float* __restrict__ z) {
  int t = blockIdx.x*256 + threadIdx.x;
  float xv[DIM];
#pragma unroll
  for (int c=0;c<DIM;c++) xv[c] = (c<16)? x0[c*L_TOT+t] : x1[(c-16)*L_TOT+t];
  float mu=0.f;
#pragma unroll
  for (int c=0;c<DIM;c++) mu += xv[c];
  mu *= (1.f/DIM);
  float var=0.f;
#pragma unroll
  for (int c=0;c<DIM;c++){ float d=xv[c]-mu; var += d*d; }
  var *= (1.f/DIM);
  float rs = rsqrtf(var + BN_EPS);
#pragma unroll
  for (int c=0;c<DIM;c++) xv[c] = (xv[c]-mu)*rs*lnw[c] + lnb[c];
  for (int j=0;j<2*DI;j++){
    float acc=0.f;
#pragma unroll
    for (int c=0;c<DIM;c++) acc += xv[c]*inw[j*DIM+c];
    if (j<DI) xs[j*L_TOT+t]=acc; else z[(j-DI)*L_TOT+t]=acc;
  }
}

// ---------------- K2a: causal depthwise conv (kw=4) + SiLU -----------------------
template<int DI>
__global__ void k_dwconv(const float* __restrict__ xs, const float* __restrict__ cw,
                         const float* __restrict__ cb, float* __restrict__ xc) {
  int idx = blockIdx.x*256 + threadIdx.x;       // d*L_TOT + t ; d wave-uniform
  int d = idx / L_TOT;
  int t = idx - d*L_TOT;
  float acc = cb[d];
#pragma unroll
  for (int k=0;k<4;k++){ int tt = t+k-3; if (tt>=0) acc += cw[d*4+k]*xs[d*L_TOT+tt]; }
  xc[idx] = acc * fsigmoid(acc);
}

// ---------------- K2b: x-proj (dbc = xc @ xp_w.T), dt = softplus(...), B, C ------
template<int DI, int DTR>
__global__ void k_xproj(const float* __restrict__ xc, const float* __restrict__ xpw,
                        const float* __restrict__ dtw, const float* __restrict__ dtb,
                        float* __restrict__ dt, float* __restrict__ Bm, float* __restrict__ Cm) {
  int t = blockIdx.x*256 + threadIdx.x;
  float xr[DI];
#pragma unroll
  for (int d=0;d<DI;d++) xr[d] = xc[d*L_TOT+t];
  float dtp[DTR];
#pragma unroll
  for (int r=0;r<DTR;r++){
    float acc=0.f;
#pragma unroll
    for (int d=0;d<DI;d++) acc += xr[d]*xpw[r*DI+d];
    dtp[r]=acc;
  }
#pragma unroll
  for (int s=0;s<16;s++){
    float aB=0.f, aC=0.f;
#pragma unroll
    for (int d=0;d<DI;d++){
      aB += xr[d]*xpw[(DTR+s)*DI+d];
      aC += xr[d]*xpw[(DTR+16+s)*DI+d];
    }
    Bm[s*L_TOT+t]=aB; Cm[s*L_TOT+t]=aC;
  }
  for (int d=0;d<DI;d++){
    float pre = dtb[d];
#pragma unroll
    for (int r=0;r<DTR;r++) pre += dtp[r]*dtw[d*DTR+r];
    dt[d*L_TOT+t] = fsoftplus(pre);
  }
}

// ---------------- K3: scan pass 1 — per-chunk aggregates (Aprod, Bacc) -----------
template<int DI>
__global__ void k_pass1(const float* __restrict__ dt, const float* __restrict__ xc,
                        const float* __restrict__ Bm, const float* __restrict__ Alog,
                        float* __restrict__ aggA, float* __restrict__ aggB) {
  constexpr int CH = DI*16;
  __shared__ float sdt[DI][16], sxc[DI][16], sB[16][17];
  int chunk = blockIdx.x; int t0 = chunk*LCHUNK;
  int tid = threadIdx.x; int d = tid>>4, s = tid&15;
  float Av = -__expf(Alog[tid]);        // A_log row-major (DI,16): index d*16+s == tid
  float Ar=1.f, Br=0.f;
  for (int tb=0; tb<LCHUNK; tb+=16){
    int bt = t0+tb;
    sdt[d][s] = dt[d*L_TOT + bt + s];
    sxc[d][s] = xc[d*L_TOT + bt + s];
    if (tid<256) sB[tid>>4][tid&15] = Bm[(tid>>4)*L_TOT + bt + (tid&15)];
    __syncthreads();
#pragma unroll
    for (int q=0;q<16;q++){
      float dtv = sdt[d][q];
      float a = __expf(dtv*Av);
      float b = dtv*sxc[d][q]*sB[s][q];
      Ar *= a; Br = a*Br + b;
    }
    __syncthreads();
  }
  int o = chunk*CH + tid;
  aggA[o]=Ar; aggB[o]=Br;
}

// ---------------- K4: sequential scan over chunk aggregates → carries ------------
__global__ void k_carry(const float* __restrict__ aggA, const float* __restrict__ aggB,
                        float* __restrict__ carry, int CH) {
  int ch = blockIdx.x*256 + threadIdx.x;
  if (ch >= CH) return;
  float h = 0.f;
  for (int c=0;c<NCHUNK;c++){
    carry[c*CH+ch] = h;
    h = aggA[c*CH+ch]*h + aggB[c*CH+ch];
  }
}

// ---------------- K5: scan pass 2 — recompute with carry, y = h·C, gate ----------
template<int DI>
__global__ void k_pass2(const float* __restrict__ dt, const float* __restrict__ xc,
                        const float* __restrict__ Bm, const float* __restrict__ Cm,
                        const float* __restrict__ z,  const float* __restrict__ Alog,
                        const float* __restrict__ Dp, const float* __restrict__ carry,
                        float* __restrict__ yg) {
  constexpr int CH = DI*16;
  __shared__ float sdt[DI][16], sxc[DI][16], sz[DI][16], sB[16][17], sC[16][17];
  int chunk = blockIdx.x; int t0 = chunk*LCHUNK;
  int tid = threadIdx.x; int d = tid>>4, s = tid&15;
  float Av = -__expf(Alog[tid]);
  float Dv = Dp[d];
  float h = carry[chunk*CH + tid];
  for (int tb=0; tb<LCHUNK; tb+=16){
    int bt = t0+tb;
    sdt[d][s] = dt[d*L_TOT + bt + s];
    sxc[d][s] = xc[d*L_TOT + bt + s];
    sz [d][s] = z [d*L_TOT + bt + s];
    if (tid<256){
      sB[tid>>4][tid&15] = Bm[(tid>>4)*L_TOT + bt + (tid&15)];
      sC[tid>>4][tid&15] = Cm[(tid>>4)*L_TOT + bt + (tid&15)];
    }
    __syncthreads();
#pragma unroll
    for (int q=0;q<16;q++){
      float dtv = sdt[d][q];
      float a = __expf(dtv*Av);
      float xcv = sxc[d][q];
      float b = dtv*xcv*sB[s][q];
      h = a*h + b;
      float p = h*sC[s][q];
      p += __shfl_xor(p,1); p += __shfl_xor(p,2);
      p += __shfl_xor(p,4); p += __shfl_xor(p,8);
      if (s==0){
        float zv = sz[d][q];
        yg[d*L_TOT + bt + q] = (p + xcv*Dv) * (zv * fsigmoid(zv));
      }
    }
    __syncthreads();
  }
}

// ---------------- K6: out-proj (yg @ out_w.T) + residual, feature-major out ------
template<int DIM, int DI>
__global__ void k_outproj(const float* __restrict__ yg, const float* __restrict__ ow,
                          const float* __restrict__ x0, const float* __restrict__ x1,
                          float* __restrict__ r) {
  int t = blockIdx.x*256 + threadIdx.x;
  float yr[DI];
#pragma unroll
  for (int d=0;d<DI;d++) yr[d] = yg[d*L_TOT+t];
  for (int i=0;i<DIM;i++){
    float acc=0.f;
#pragma unroll
    for (int d=0;d<DI;d++) acc += yr[d]*ow[i*DI+d];
    float res = (i<16)? x0[i*L_TOT+t] : x1[(i-16)*L_TOT+t];
    r[i*L_TOT+t] = acc + res;
  }
}

// ---------------- conv3d 3x3x3 pad1, thread per (co,t), wave-uniform co ----------
template<int IC>
__global__ void k_conv3d(const float* __restrict__ in, const float* __restrict__ w,
                         const float* __restrict__ bias, float* __restrict__ out) {
  int idx = blockIdx.x*256 + threadIdx.x;       // co*L_TOT + t
  int co = idx / L_TOT;
  int t  = idx - co*L_TOT;
  int zz = t / 2304;
  int r2 = t - zz*2304;
  int yy = r2 / 48;
  int xx = r2 - yy*48;
  float acc = bias[co];
  int off[27];
  unsigned msk = 0u;
#pragma unroll
  for (int dz=-1;dz<=1;dz++)
#pragma unroll
    for (int dy=-1;dy<=1;dy++)
#pragma unroll
      for (int dx=-1;dx<=1;dx++){
        int kk = (dz+1)*9+(dy+1)*3+(dx+1);
        off[kk] = dz*2304+dy*48+dx;
        bool v = ((unsigned)(zz+dz)<16u) && ((unsigned)(yy+dy)<48u) && ((unsigned)(xx+dx)<48u);
        if (v) msk |= (1u<<kk);
      }
  const float* wc = w + co*IC*27;
  for (int ic=0; ic<IC; ic++){
    const float* p  = in + ic*L_TOT + t;
    const float* wi = wc + ic*27;
#pragma unroll
    for (int kk=0;kk<27;kk++)
      if (msk & (1u<<kk)) acc += wi[kk]*p[off[kk]];
  }
  out[idx] = acc;
}

// ---------------- BN: block-per-channel reduce (sum, sumsq) ----------------------
__global__ void k_bn_reduce(const float* __restrict__ x, float* __restrict__ stats) {
  int c = blockIdx.x; int tid = threadIdx.x;
  float s=0.f, s2=0.f;
  for (int i=tid;i<L_TOT;i+=256){ float v = x[c*L_TOT+i]; s+=v; s2+=v*v; }
  for (int o=1;o<64;o<<=1){ s += __shfl_xor(s,o); s2 += __shfl_xor(s2,o); }
  __shared__ float ls[4], ls2[4];
  int wv = tid>>6;
  if ((tid&63)==0){ ls[wv]=s; ls2[wv]=s2; }
  __syncthreads();
  if (tid==0){
    stats[2*c]   = ls[0]+ls[1]+ls[2]+ls[3];
    stats[2*c+1] = ls2[0]+ls2[1]+ls2[2]+ls2[3];
  }
}

__global__ void k_bn_norm(const float* __restrict__ raw, const float* __restrict__ stats,
                          const float* __restrict__ g, const float* __restrict__ b,
                          float* __restrict__ out) {
  int idx = blockIdx.x*256 + threadIdx.x;       // c*L_TOT + t
  int c = idx / L_TOT;
  float m = stats[2*c]*(1.f/L_TOT);
  float v = stats[2*c+1]*(1.f/L_TOT) - m*m;
  out[idx] = (raw[idx]-m)*rsqrtf(v+BN_EPS)*g[c] + b[c];
}

// =================================================================================
extern "C" void kernel_launch(void* const* d_in, const int* in_sizes, int n_in,
                              void* d_out, int out_size, void* d_ws, size_t ws_size,
                              hipStream_t stream) {
  const float* l        = (const float*)d_in[0];
  const float* s        = (const float*)d_in[1];
  const float* m1_ln_w  = (const float*)d_in[2];
  const float* m1_ln_b  = (const float*)d_in[3];
  const float* m1_in_w  = (const float*)d_in[4];
  const float* m1_cw    = (const float*)d_in[5];
  const float* m1_cb    = (const float*)d_in[6];
  const float* m1_xp_w  = (const float*)d_in[7];
  const float* m1_dt_w  = (const float*)d_in[8];
  const float* m1_dt_b  = (const float*)d_in[9];
  const float* m1_Alog  = (const float*)d_in[10];
  const float* m1_D     = (const float*)d_in[11];
  const float* m1_out_w = (const float*)d_in[12];
  const float* m2_ln_w  = (const float*)d_in[13];
  const float* m2_ln_b  = (const float*)d_in[14];
  const float* m2_in_w  = (const float*)d_in[15];
  const float* m2_cw    = (const float*)d_in[16];
  const float* m2_cb    = (const float*)d_in[17];
  const float* m2_xp_w  = (const float*)d_in[18];
  const float* m2_dt_w  = (const float*)d_in[19];
  const float* m2_dt_b  = (const float*)d_in[20];
  const float* m2_Alog  = (const float*)d_in[21];
  const float* m2_D     = (const float*)d_in[22];
  const float* m2_out_w = (const float*)d_in[23];
  const float* c1_w     = (const float*)d_in[24];
  const float* c1_b     = (const float*)d_in[25];
  const float* bn1_g    = (const float*)d_in[26];
  const float* bn1_b    = (const float*)d_in[27];
  const float* c2_w     = (const float*)d_in[28];
  const float* c2_b     = (const float*)d_in[29];
  const float* bn2_g    = (const float*)d_in[30];
  const float* bn2_b    = (const float*)d_in[31];

  float* ws = (float*)d_ws;
  const size_t L = L_TOT;
  // ---- stage-1 buffers (feature-major [f][t]) ----
  float* xs1   = ws;             // 64L
  float* z1    = ws + 64*L;      // 64L
  float* xc1   = ws + 128*L;     // 64L
  float* dt1   = ws + 192*L;     // 64L
  float* B1    = ws + 256*L;     // 16L
  float* C1    = ws + 272*L;     // 16L
  float* yg1   = ws + 288*L;     // 64L
  float* r1    = ws + 352*L;     // 32L
  float* aggA  = ws + 384*L;           // NCHUNK*1024
  float* aggB  = aggA + NCHUNK*1024;   // NCHUNK*1024
  float* carry = aggB + NCHUNK*1024;   // NCHUNK*1024
  float* stats1 = carry + NCHUNK*1024; // 32
  float* stats2 = stats1 + 32;         // 32
  // ---- stage-2 aliases over dead stage-1 buffers ----
  float* conv1raw = ws;            // 16L  (xs1 dead)
  float* bn1out   = ws + 16*L;     // 16L
  float* xs2 = ws + 128*L;         // 32L  (xc1 dead)
  float* z2  = ws + 160*L;         // 32L
  float* xc2 = ws + 192*L;         // 32L  (dt1 dead)
  float* dt2 = ws + 224*L;         // 32L
  float* B2  = ws + 256*L;         // 16L
  float* C2  = ws + 272*L;         // 16L
  float* yg2 = ws + 288*L;         // 32L
  float* r2  = ws + 320*L;         // 16L
  float* conv2raw = ws + 336*L;    // 16L

  // ================= stage 1: mamba(dim=32, di=64) + conv1 + bn1 =================
  k_front<32,64><<<144,256,0,stream>>>(l, s, m1_ln_w, m1_ln_b, m1_in_w, xs1, z1);
  k_dwconv<64><<<9216,256,0,stream>>>(xs1, m1_cw, m1_cb, xc1);
  k_xproj<64,2><<<144,256,0,stream>>>(xc1, m1_xp_w, m1_dt_w, m1_dt_b, dt1, B1, C1);
  k_pass1<64><<<NCHUNK,1024,0,stream>>>(dt1, xc1, B1, m1_Alog, aggA, aggB);
  k_carry<<<4,256,0,stream>>>(aggA, aggB, carry, 1024);
  k_pass2<64><<<NCHUNK,1024,0,stream>>>(dt1, xc1, B1, C1, z1, m1_Alog, m1_D, carry, yg1);
  k_outproj<32,64><<<144,256,0,stream>>>(yg1, m1_out_w, l, s, r1);
  k_conv3d<32><<<2304,256,0,stream>>>(r1, c1_w, c1_b, conv1raw);
  k_bn_reduce<<<16,256,0,stream>>>(conv1raw, stats1);
  k_bn_norm<<<2304,256,0,stream>>>(conv1raw, stats1, bn1_g, bn1_b, bn1out);

  // ================= stage 2: mamba(dim=16, di=32) + conv2 + bn2 =================
  k_front<16,32><<<144,256,0,stream>>>(bn1out, bn1out, m2_ln_w, m2_ln_b, m2_in_w, xs2, z2);
  k_dwconv<32><<<4608,256,0,stream>>>(xs2, m2_cw, m2_cb, xc2);
  k_xproj<32,1><<<144,256,0,stream>>>(xc2, m2_xp_w, m2_dt_w, m2_dt_b, dt2, B2, C2);
  k_pass1<32><<<NCHUNK,512,0,stream>>>(dt2, xc2, B2, m2_Alog, aggA, aggB);
  k_carry<<<2,256,0,stream>>>(aggA, aggB, carry, 512);
  k_pass2<32><<<NCHUNK,512,0,stream>>>(dt2, xc2, B2, C2, z2, m2_Alog, m2_D, carry, yg2);
  k_outproj<16,32><<<144,256,0,stream>>>(yg2, m2_out_w, bn1out, bn1out, r2);
  k_conv3d<16><<<2304,256,0,stream>>>(r2, c2_w, c2_b, conv2raw);
  k_bn_reduce<<<16,256,0,stream>>>(conv2raw, stats2);
  k_bn_norm<<<2304,256,0,stream>>>(conv2raw, stats2, bn2_g, bn2_b, (float*)d_out);
}

// Round 2
// 638.941 us; speedup vs baseline: 1.3857x; 1.3857x over previous
//
#include <hip/hip_runtime.h>
#include <math.h>

#define L_TOT 36864
#define LCHUNK 144
#define NCHUNK 256
#define BN_EPS 1e-5f
#define PCH 45000   // padded channel stride: 18*50*50

__device__ __forceinline__ float fsigmoid(float x){ return 1.f/(1.f+__expf(-x)); }
__device__ __forceinline__ float fsoftplus(float x){ return (x>20.f)? x : log1pf(__expf(x)); }

// ---------------- zero-fill (for padded halos) -----------------------------------
__global__ void k_zero(float* __restrict__ p, int n) {
  int i = blockIdx.x*256 + threadIdx.x;
  if (i < n) p[i] = 0.f;
}

// ---------------- K1: LayerNorm + in-proj (xz = xn @ in_w.T, split into xs/z) ----
template<int DIM, int DI>
__global__ void k_front(const float* __restrict__ x0, const float* __restrict__ x1,
                        const float* __restrict__ lnw, const float* __restrict__ lnb,
                        const float* __restrict__ inw,
                        float* __restrict__ xs, float* __restrict__ z) {
  int t = blockIdx.x*256 + threadIdx.x;
  float xv[DIM];
#pragma unroll
  for (int c=0;c<DIM;c++) xv[c] = (c<16)? x0[c*L_TOT+t] : x1[(c-16)*L_TOT+t];
  float mu=0.f;
#pragma unroll
  for (int c=0;c<DIM;c++) mu += xv[c];
  mu *= (1.f/DIM);
  float var=0.f;
#pragma unroll
  for (int c=0;c<DIM;c++){ float d=xv[c]-mu; var += d*d; }
  var *= (1.f/DIM);
  float rs = rsqrtf(var + BN_EPS);
#pragma unroll
  for (int c=0;c<DIM;c++) xv[c] = (xv[c]-mu)*rs*lnw[c] + lnb[c];
  for (int j=0;j<2*DI;j++){
    float acc=0.f;
#pragma unroll
    for (int c=0;c<DIM;c++) acc += xv[c]*inw[j*DIM+c];
    if (j<DI) xs[j*L_TOT+t]=acc; else z[(j-DI)*L_TOT+t]=acc;
  }
}

// ---------------- K2a: causal depthwise conv (kw=4) + SiLU -----------------------
template<int DI>
__global__ void k_dwconv(const float* __restrict__ xs, const float* __restrict__ cw,
                         const float* __restrict__ cb, float* __restrict__ xc) {
  int idx = blockIdx.x*256 + threadIdx.x;       // d*L_TOT + t ; d wave-uniform
  int d = idx / L_TOT;
  int t = idx - d*L_TOT;
  float acc = cb[d];
#pragma unroll
  for (int k=0;k<4;k++){ int tt = t+k-3; if (tt>=0) acc += cw[d*4+k]*xs[d*L_TOT+tt]; }
  xc[idx] = acc * fsigmoid(acc);
}

// ---------------- K2b: x-proj (dbc = xc @ xp_w.T), dt = softplus(...), B, C ------
template<int DI, int DTR>
__global__ void k_xproj(const float* __restrict__ xc, const float* __restrict__ xpw,
                        const float* __restrict__ dtw, const float* __restrict__ dtb,
                        float* __restrict__ dt, float* __restrict__ Bm, float* __restrict__ Cm) {
  int t = blockIdx.x*256 + threadIdx.x;
  float xr[DI];
#pragma unroll
  for (int d=0;d<DI;d++) xr[d] = xc[d*L_TOT+t];
  float dtp[DTR];
#pragma unroll
  for (int r=0;r<DTR;r++){
    float acc=0.f;
#pragma unroll
    for (int d=0;d<DI;d++) acc += xr[d]*xpw[r*DI+d];
    dtp[r]=acc;
  }
#pragma unroll
  for (int s=0;s<16;s++){
    float aB=0.f, aC=0.f;
#pragma unroll
    for (int d=0;d<DI;d++){
      aB += xr[d]*xpw[(DTR+s)*DI+d];
      aC += xr[d]*xpw[(DTR+16+s)*DI+d];
    }
    Bm[s*L_TOT+t]=aB; Cm[s*L_TOT+t]=aC;
  }
  for (int d=0;d<DI;d++){
    float pre = dtb[d];
#pragma unroll
    for (int r=0;r<DTR;r++) pre += dtp[r]*dtw[d*DTR+r];
    dt[d*L_TOT+t] = fsoftplus(pre);
  }
}

// ---------------- K3: scan pass 1 — per-chunk aggregates (Aprod, Bacc) -----------
template<int DI>
__global__ void k_pass1(const float* __restrict__ dt, const float* __restrict__ xc,
                        const float* __restrict__ Bm, const float* __restrict__ Alog,
                        float* __restrict__ aggA, float* __restrict__ aggB) {
  constexpr int CH = DI*16;
  __shared__ float sdt[DI][16], sxc[DI][16], sB[16][17];
  int chunk = blockIdx.x; int t0 = chunk*LCHUNK;
  int tid = threadIdx.x; int d = tid>>4, s = tid&15;
  float Av = -__expf(Alog[tid]);        // A_log row-major (DI,16): index d*16+s == tid
  float Ar=1.f, Br=0.f;
  for (int tb=0; tb<LCHUNK; tb+=16){
    int bt = t0+tb;
    sdt[d][s] = dt[d*L_TOT + bt + s];
    sxc[d][s] = xc[d*L_TOT + bt + s];
    if (tid<256) sB[tid>>4][tid&15] = Bm[(tid>>4)*L_TOT + bt + (tid&15)];
    __syncthreads();
#pragma unroll
    for (int q=0;q<16;q++){
      float dtv = sdt[d][q];
      float a = __expf(dtv*Av);
      float b = dtv*sxc[d][q]*sB[s][q];
      Ar *= a; Br = a*Br + b;
    }
    __syncthreads();
  }
  int o = chunk*CH + tid;
  aggA[o]=Ar; aggB[o]=Br;
}

// ---------------- K4: sequential scan over chunk aggregates → carries ------------
__global__ void k_carry(const float* __restrict__ aggA, const float* __restrict__ aggB,
                        float* __restrict__ carry, int CH) {
  int ch = blockIdx.x*256 + threadIdx.x;
  if (ch >= CH) return;
  float h = 0.f;
  for (int c=0;c<NCHUNK;c++){
    carry[c*CH+ch] = h;
    h = aggA[c*CH+ch]*h + aggB[c*CH+ch];
  }
}

// ---------------- K5: scan pass 2 — recompute with carry, y = h·C, gate ----------
template<int DI>
__global__ void k_pass2(const float* __restrict__ dt, const float* __restrict__ xc,
                        const float* __restrict__ Bm, const float* __restrict__ Cm,
                        const float* __restrict__ z,  const float* __restrict__ Alog,
                        const float* __restrict__ Dp, const float* __restrict__ carry,
                        float* __restrict__ yg) {
  constexpr int CH = DI*16;
  __shared__ float sdt[DI][16], sxc[DI][16], sz[DI][16], sB[16][17], sC[16][17];
  int chunk = blockIdx.x; int t0 = chunk*LCHUNK;
  int tid = threadIdx.x; int d = tid>>4, s = tid&15;
  float Av = -__expf(Alog[tid]);
  float Dv = Dp[d];
  float h = carry[chunk*CH + tid];
  for (int tb=0; tb<LCHUNK; tb+=16){
    int bt = t0+tb;
    sdt[d][s] = dt[d*L_TOT + bt + s];
    sxc[d][s] = xc[d*L_TOT + bt + s];
    sz [d][s] = z [d*L_TOT + bt + s];
    if (tid<256){
      sB[tid>>4][tid&15] = Bm[(tid>>4)*L_TOT + bt + (tid&15)];
      sC[tid>>4][tid&15] = Cm[(tid>>4)*L_TOT + bt + (tid&15)];
    }
    __syncthreads();
#pragma unroll
    for (int q=0;q<16;q++){
      float dtv = sdt[d][q];
      float a = __expf(dtv*Av);
      float xcv = sxc[d][q];
      float b = dtv*xcv*sB[s][q];
      h = a*h + b;
      float p = h*sC[s][q];
      p += __shfl_xor(p,1); p += __shfl_xor(p,2);
      p += __shfl_xor(p,4); p += __shfl_xor(p,8);
      if (s==0){
        float zv = sz[d][q];
        yg[d*L_TOT + bt + q] = (p + xcv*Dv) * (zv * fsigmoid(zv));
      }
    }
    __syncthreads();
  }
}

// ---------------- K6: out-proj + residual → PADDED layout ------------------------
template<int DIM, int DI>
__global__ void k_outproj_p(const float* __restrict__ yg, const float* __restrict__ ow,
                            const float* __restrict__ x0, const float* __restrict__ x1,
                            float* __restrict__ rp) {
  int t = blockIdx.x*256 + threadIdx.x;
  int zz = t / 2304;
  int r2 = t - zz*2304;
  int yy = r2 / 48;
  int xx = r2 - yy*48;
  int pb = (zz+1)*2500 + (yy+1)*50 + (xx+1);
  float yr[DI];
#pragma unroll
  for (int d=0;d<DI;d++) yr[d] = yg[d*L_TOT+t];
  for (int i=0;i<DIM;i++){
    float acc=0.f;
#pragma unroll
    for (int d=0;d<DI;d++) acc += yr[d]*ow[i*DI+d];
    float res = (i<16)? x0[i*L_TOT+t] : x1[(i-16)*L_TOT+t];
    rp[i*PCH+pb] = acc + res;
  }
}

// ---------------- conv3d 3x3x3: padded input, 4 co per thread --------------------
template<int IC>
__global__ __launch_bounds__(256) void k_conv3d_p(const float* __restrict__ in,
                         const float* __restrict__ w,
                         const float* __restrict__ bias, float* __restrict__ out) {
  int t = blockIdx.x*256 + threadIdx.x;         // 0..L_TOT-1
  int cog = blockIdx.y;                         // co group (4 co each)
  int co0 = cog*4;
  int zz = t / 2304;
  int r2 = t - zz*2304;
  int yy = r2 / 48;
  int xx = r2 - yy*48;
  int pb = (zz+1)*2500 + (yy+1)*50 + (xx+1);
  float acc0 = bias[co0+0], acc1 = bias[co0+1], acc2 = bias[co0+2], acc3 = bias[co0+3];
  for (int ic=0; ic<IC; ic++){
    const float* p = in + ic*PCH + pb;
    float v[27];
#pragma unroll
    for (int dz=0;dz<3;dz++)
#pragma unroll
      for (int dy=0;dy<3;dy++)
#pragma unroll
        for (int dx=0;dx<3;dx++)
          v[dz*9+dy*3+dx] = p[(dz-1)*2500 + (dy-1)*50 + (dx-1)];
    const float* wp = w + co0*IC*27 + ic*27;
#pragma unroll
    for (int kk=0;kk<27;kk++){
      acc0 += wp[kk]          * v[kk];
      acc1 += wp[IC*27+kk]    * v[kk];
      acc2 += wp[2*IC*27+kk]  * v[kk];
      acc3 += wp[3*IC*27+kk]  * v[kk];
    }
  }
  out[(co0+0)*L_TOT + t] = acc0;
  out[(co0+1)*L_TOT + t] = acc1;
  out[(co0+2)*L_TOT + t] = acc2;
  out[(co0+3)*L_TOT + t] = acc3;
}

// ---------------- BN: block-per-channel reduce (sum, sumsq) ----------------------
__global__ void k_bn_reduce(const float* __restrict__ x, float* __restrict__ stats) {
  int c = blockIdx.x; int tid = threadIdx.x;
  float s=0.f, s2=0.f;
  for (int i=tid;i<L_TOT;i+=256){ float v = x[c*L_TOT+i]; s+=v; s2+=v*v; }
  for (int o=1;o<64;o<<=1){ s += __shfl_xor(s,o); s2 += __shfl_xor(s2,o); }
  __shared__ float ls[4], ls2[4];
  int wv = tid>>6;
  if ((tid&63)==0){ ls[wv]=s; ls2[wv]=s2; }
  __syncthreads();
  if (tid==0){
    stats[2*c]   = ls[0]+ls[1]+ls[2]+ls[3];
    stats[2*c+1] = ls2[0]+ls2[1]+ls2[2]+ls2[3];
  }
}

__global__ void k_bn_norm(const float* __restrict__ raw, const float* __restrict__ stats,
                          const float* __restrict__ g, const float* __restrict__ b,
                          float* __restrict__ out) {
  int idx = blockIdx.x*256 + threadIdx.x;       // c*L_TOT + t
  int c = idx / L_TOT;
  float m = stats[2*c]*(1.f/L_TOT);
  float v = stats[2*c+1]*(1.f/L_TOT) - m*m;
  out[idx] = (raw[idx]-m)*rsqrtf(v+BN_EPS)*g[c] + b[c];
}

// =================================================================================
extern "C" void kernel_launch(void* const* d_in, const int* in_sizes, int n_in,
                              void* d_out, int out_size, void* d_ws, size_t ws_size,
                              hipStream_t stream) {
  const float* l        = (const float*)d_in[0];
  const float* s        = (const float*)d_in[1];
  const float* m1_ln_w  = (const float*)d_in[2];
  const float* m1_ln_b  = (const float*)d_in[3];
  const float* m1_in_w  = (const float*)d_in[4];
  const float* m1_cw    = (const float*)d_in[5];
  const float* m1_cb    = (const float*)d_in[6];
  const float* m1_xp_w  = (const float*)d_in[7];
  const float* m1_dt_w  = (const float*)d_in[8];
  const float* m1_dt_b  = (const float*)d_in[9];
  const float* m1_Alog  = (const float*)d_in[10];
  const float* m1_D     = (const float*)d_in[11];
  const float* m1_out_w = (const float*)d_in[12];
  const float* m2_ln_w  = (const float*)d_in[13];
  const float* m2_ln_b  = (const float*)d_in[14];
  const float* m2_in_w  = (const float*)d_in[15];
  const float* m2_cw    = (const float*)d_in[16];
  const float* m2_cb    = (const float*)d_in[17];
  const float* m2_xp_w  = (const float*)d_in[18];
  const float* m2_dt_w  = (const float*)d_in[19];
  const float* m2_dt_b  = (const float*)d_in[20];
  const float* m2_Alog  = (const float*)d_in[21];
  const float* m2_D     = (const float*)d_in[22];
  const float* m2_out_w = (const float*)d_in[23];
  const float* c1_w     = (const float*)d_in[24];
  const float* c1_b     = (const float*)d_in[25];
  const float* bn1_g    = (const float*)d_in[26];
  const float* bn1_b    = (const float*)d_in[27];
  const float* c2_w     = (const float*)d_in[28];
  const float* c2_b     = (const float*)d_in[29];
  const float* bn2_g    = (const float*)d_in[30];
  const float* bn2_b    = (const float*)d_in[31];

  float* ws = (float*)d_ws;
  const size_t L = L_TOT;
  // ---- stage-1 buffers (feature-major [f][t]); aggressive lifetime aliasing ----
  float* xs1   = ws;               // 0..64L   (dead after dwconv1)
  float* yg1   = ws;               // alias: written by pass2_1
  float* conv1raw = ws;            // alias: 0..16L, written by conv1 (yg1 dead)
  float* z1    = ws + 64*L;        // 64..128L (dead after pass2_1)
  float* r1p   = ws + 64*L;        // alias: padded 32ch*45000 = 39.07L
  float* xc1   = ws + 128*L;       // 128..192L (dead after pass2_1)
  float* bn1out= ws + 128*L;       // alias: 128..144L (lives through stage 2)
  float* xs2   = ws + 144*L;       // 144..176L
  float* dt1   = ws + 192*L;       // 192..256L (dead after pass2_1)
  float* z2    = ws + 192*L;       // alias: 192..224L
  float* xc2   = ws + 224*L;       // alias: 224..256L
  float* B1    = ws + 256*L;       // 256..272L (B2 aliases later)
  float* C1    = ws + 272*L;       // 272..288L (C2 aliases later)
  float* B2    = B1;
  float* C2    = C1;
  float* dt2   = ws + 288*L;       // 288..320L
  float* yg2   = ws + 320*L;       // 320..352L
  float* aggA  = ws + 352*L;           // 256*1024
  float* aggB  = aggA + NCHUNK*1024;
  float* carry = aggB + NCHUNK*1024;
  float* stats1 = carry + NCHUNK*1024; // 32
  float* stats2 = stats1 + 32;         // 32
  float* r2p   = ws + 352*L;       // alias over agg (dead after pass2_2): 16ch*45000 = 19.54L
  float* conv2raw = ws + 374*L;    // 374..390L

  // ================= stage 1: mamba(dim=32, di=64) + conv1 + bn1 =================
  k_front<32,64><<<144,256,0,stream>>>(l, s, m1_ln_w, m1_ln_b, m1_in_w, xs1, z1);
  k_dwconv<64><<<9216,256,0,stream>>>(xs1, m1_cw, m1_cb, xc1);
  k_xproj<64,2><<<144,256,0,stream>>>(xc1, m1_xp_w, m1_dt_w, m1_dt_b, dt1, B1, C1);
  k_pass1<64><<<NCHUNK,1024,0,stream>>>(dt1, xc1, B1, m1_Alog, aggA, aggB);
  k_carry<<<4,256,0,stream>>>(aggA, aggB, carry, 1024);
  k_pass2<64><<<NCHUNK,1024,0,stream>>>(dt1, xc1, B1, C1, z1, m1_Alog, m1_D, carry, yg1);
  k_zero<<<(32*PCH+255)/256,256,0,stream>>>(r1p, 32*PCH);          // z1 dead now
  k_outproj_p<32,64><<<144,256,0,stream>>>(yg1, m1_out_w, l, s, r1p);
  k_conv3d_p<32><<<dim3(144,4),256,0,stream>>>(r1p, c1_w, c1_b, conv1raw);
  k_bn_reduce<<<16,256,0,stream>>>(conv1raw, stats1);
  k_bn_norm<<<2304,256,0,stream>>>(conv1raw, stats1, bn1_g, bn1_b, bn1out);

  // ================= stage 2: mamba(dim=16, di=32) + conv2 + bn2 =================
  k_front<16,32><<<144,256,0,stream>>>(bn1out, bn1out, m2_ln_w, m2_ln_b, m2_in_w, xs2, z2);
  k_dwconv<32><<<4608,256,0,stream>>>(xs2, m2_cw, m2_cb, xc2);
  k_xproj<32,1><<<144,256,0,stream>>>(xc2, m2_xp_w, m2_dt_w, m2_dt_b, dt2, B2, C2);
  k_pass1<32><<<NCHUNK,512,0,stream>>>(dt2, xc2, B2, m2_Alog, aggA, aggB);
  k_carry<<<2,256,0,stream>>>(aggA, aggB, carry, 512);
  k_pass2<32><<<NCHUNK,512,0,stream>>>(dt2, xc2, B2, C2, z2, m2_Alog, m2_D, carry, yg2);
  k_zero<<<(16*PCH+255)/256,256,0,stream>>>(r2p, 16*PCH);          // agg/carry dead now
  k_outproj_p<16,32><<<144,256,0,stream>>>(yg2, m2_out_w, bn1out, bn1out, r2p);
  k_conv3d_p<16><<<dim3(144,4),256,0,stream>>>(r2p, c2_w, c2_b, conv2raw);
  k_bn_reduce<<<16,256,0,stream>>>(conv2raw, stats2);
  k_bn_norm<<<2304,256,0,stream>>>(conv2raw, stats2, bn2_g, bn2_b, (float*)d_out);
}